// Round 1
// baseline (97.453 us; speedup 1.0000x reference)
//
#include <hip/hip_runtime.h>

#define NIMG 2
#define CCH 256
#define FH 128
#define FW 128
#define FHW (FH * FW)
#define OUTH 7
#define OUTW 7
#define NPIX 49
#define KROIS 1024
#define SCALE 0.0625f
#define OPITCH 260  // 49 rows x 260 floats; 260*4B = 1040B row, 16B-aligned, odd-ish bank rotation

// ---------------- NCHW -> NHWC transpose (per image: 256 x 16384 -> 16384 x 256) ----------------
__global__ __launch_bounds__(256) void nchw_to_nhwc(const float* __restrict__ in,
                                                    float* __restrict__ out) {
    __shared__ float tile[32][33];
    const int b   = blockIdx.z;
    const int hw0 = blockIdx.x << 5;
    const int c0  = blockIdx.y << 5;
    const int tx  = threadIdx.x;
    const int ty  = threadIdx.y;
    const float* src = in  + (size_t)b * CCH * FHW;
    float*       dst = out + (size_t)b * FHW * CCH;
#pragma unroll
    for (int i = 0; i < 32; i += 8)
        tile[ty + i][tx] = src[(size_t)(c0 + ty + i) * FHW + hw0 + tx];
    __syncthreads();
#pragma unroll
    for (int i = 0; i < 32; i += 8)
        dst[(size_t)(hw0 + ty + i) * CCH + c0 + tx] = tile[tx][ty + i];
}

// ---------------- main RoIAlign on NHWC ----------------
__global__ __launch_bounds__(512) void roi_align_nhwc(const float* __restrict__ nhwc,
                                                      const float* __restrict__ rois,
                                                      float* __restrict__ out) {
    __shared__ float obuf[NPIX * OPITCH];  // 50,960 B
    const int k    = blockIdx.x;
    const int lane = threadIdx.x & 63;
    const int wave = threadIdx.x >> 6;

    const float* r = rois + k * 5;
    const int b = (int)r[0];
    const float x1 = __fsub_rn(__fmul_rn(r[1], SCALE), 0.5f);
    const float y1 = __fsub_rn(__fmul_rn(r[2], SCALE), 0.5f);
    const float x2 = __fsub_rn(__fmul_rn(r[3], SCALE), 0.5f);
    const float y2 = __fsub_rn(__fmul_rn(r[4], SCALE), 0.5f);
    const float bw = __fdiv_rn(__fsub_rn(x2, x1), (float)OUTW);
    const float bh = __fdiv_rn(__fsub_rn(y2, y1), (float)OUTH);
    const float* fb = nhwc + (size_t)b * FHW * CCH + (lane << 2);

    for (int pix = wave; pix < NPIX; pix += 8) {
        const int ph = pix / 7;
        const int pw = pix - ph * 7;
        float acc0 = 0.f, acc1 = 0.f, acc2 = 0.f, acc3 = 0.f;
#pragma unroll
        for (int s = 0; s < 4; ++s) {
            const int sy = s >> 1, sx = s & 1;
            const float fy = (float)ph + (sy ? 0.75f : 0.25f);  // exact
            const float fx = (float)pw + (sx ? 0.75f : 0.25f);  // exact
            const float y = __fadd_rn(y1, __fmul_rn(fy, bh));   // match numpy rounding
            const float x = __fadd_rn(x1, __fmul_rn(fx, bw));
            if (y > -1.0f && y < (float)FH && x > -1.0f && x < (float)FW) {
                const float yc = fmaxf(y, 0.0f);
                const float xc = fmaxf(x, 0.0f);
                int y0 = (int)yc; if (y0 > FH - 1) y0 = FH - 1;
                int x0 = (int)xc; if (x0 > FW - 1) x0 = FW - 1;
                const int y1i = min(y0 + 1, FH - 1);
                const int x1i = min(x0 + 1, FW - 1);
                const float ly = fminf(yc - (float)y0, 1.0f);
                const float lx = fminf(xc - (float)x0, 1.0f);
                const float hy = 1.0f - ly, hx = 1.0f - lx;
                const float w00 = hy * hx, w01 = hy * lx, w10 = ly * hx, w11 = ly * lx;
                const float4 v00 = *(const float4*)(fb + ((size_t)(y0  * FW + x0 ) << 8));
                const float4 v01 = *(const float4*)(fb + ((size_t)(y0  * FW + x1i) << 8));
                const float4 v10 = *(const float4*)(fb + ((size_t)(y1i * FW + x0 ) << 8));
                const float4 v11 = *(const float4*)(fb + ((size_t)(y1i * FW + x1i) << 8));
                acc0 += w00 * v00.x + w01 * v01.x + w10 * v10.x + w11 * v11.x;
                acc1 += w00 * v00.y + w01 * v01.y + w10 * v10.y + w11 * v11.y;
                acc2 += w00 * v00.z + w01 * v01.z + w10 * v10.z + w11 * v11.z;
                acc3 += w00 * v00.w + w01 * v01.w + w10 * v10.w + w11 * v11.w;
            }
        }
        float4 res = make_float4(acc0 * 0.25f, acc1 * 0.25f, acc2 * 0.25f, acc3 * 0.25f);
        *(float4*)(&obuf[pix * OPITCH + (lane << 2)]) = res;
    }
    __syncthreads();

    // coalesced writeout: out[k][c][pix], 12544 contiguous floats per k
    float* op = out + (size_t)k * (CCH * NPIX);
    for (int f4 = threadIdx.x; f4 < (CCH * NPIX) / 4; f4 += 512) {
        const int f = f4 << 2;
        float4 o;
        {
            const int fi = f + 0; const int c = fi / NPIX; const int p = fi - c * NPIX;
            o.x = obuf[p * OPITCH + c];
        }
        {
            const int fi = f + 1; const int c = fi / NPIX; const int p = fi - c * NPIX;
            o.y = obuf[p * OPITCH + c];
        }
        {
            const int fi = f + 2; const int c = fi / NPIX; const int p = fi - c * NPIX;
            o.z = obuf[p * OPITCH + c];
        }
        {
            const int fi = f + 3; const int c = fi / NPIX; const int p = fi - c * NPIX;
            o.w = obuf[p * OPITCH + c];
        }
        *(float4*)(op + f) = o;
    }
}

// ---------------- fallback: direct NCHW, one thread per output element ----------------
__global__ __launch_bounds__(256) void roi_align_naive(const float* __restrict__ feat,
                                                       const float* __restrict__ rois,
                                                       float* __restrict__ out) {
    const size_t idx = (size_t)blockIdx.x * 256 + threadIdx.x;
    const size_t total = (size_t)KROIS * CCH * NPIX;
    if (idx >= total) return;
    const int pix = (int)(idx % NPIX);
    const int t1  = (int)(idx / NPIX);
    const int c   = t1 % CCH;
    const int k   = t1 / CCH;
    const int ph = pix / 7;
    const int pw = pix - ph * 7;

    const float* r = rois + k * 5;
    const int b = (int)r[0];
    const float x1 = __fsub_rn(__fmul_rn(r[1], SCALE), 0.5f);
    const float y1 = __fsub_rn(__fmul_rn(r[2], SCALE), 0.5f);
    const float x2 = __fsub_rn(__fmul_rn(r[3], SCALE), 0.5f);
    const float y2 = __fsub_rn(__fmul_rn(r[4], SCALE), 0.5f);
    const float bw = __fdiv_rn(__fsub_rn(x2, x1), (float)OUTW);
    const float bh = __fdiv_rn(__fsub_rn(y2, y1), (float)OUTH);
    const float* fp = feat + (size_t)(b * CCH + c) * FHW;

    float acc = 0.f;
#pragma unroll
    for (int s = 0; s < 4; ++s) {
        const int sy = s >> 1, sx = s & 1;
        const float fy = (float)ph + (sy ? 0.75f : 0.25f);
        const float fx = (float)pw + (sx ? 0.75f : 0.25f);
        const float y = __fadd_rn(y1, __fmul_rn(fy, bh));
        const float x = __fadd_rn(x1, __fmul_rn(fx, bw));
        if (y > -1.0f && y < (float)FH && x > -1.0f && x < (float)FW) {
            const float yc = fmaxf(y, 0.0f);
            const float xc = fmaxf(x, 0.0f);
            int y0 = (int)yc; if (y0 > FH - 1) y0 = FH - 1;
            int x0 = (int)xc; if (x0 > FW - 1) x0 = FW - 1;
            const int y1i = min(y0 + 1, FH - 1);
            const int x1i = min(x0 + 1, FW - 1);
            const float ly = fminf(yc - (float)y0, 1.0f);
            const float lx = fminf(xc - (float)x0, 1.0f);
            const float hy = 1.0f - ly, hx = 1.0f - lx;
            acc += (hy * hx) * fp[y0  * FW + x0 ] + (hy * lx) * fp[y0  * FW + x1i]
                 + (ly * hx) * fp[y1i * FW + x0 ] + (ly * lx) * fp[y1i * FW + x1i];
        }
    }
    out[idx] = acc * 0.25f;
}

extern "C" void kernel_launch(void* const* d_in, const int* in_sizes, int n_in,
                              void* d_out, int out_size, void* d_ws, size_t ws_size,
                              hipStream_t stream) {
    const float* feat = (const float*)d_in[0];
    const float* rois = (const float*)d_in[1];
    float* out = (float*)d_out;

    const size_t nhwc_bytes = (size_t)NIMG * CCH * FHW * sizeof(float);  // 33.5 MB
    if (ws_size >= nhwc_bytes) {
        float* nhwc = (float*)d_ws;
        dim3 tg(FHW / 32, CCH / 32, NIMG);
        nchw_to_nhwc<<<tg, dim3(32, 8), 0, stream>>>(feat, nhwc);
        roi_align_nhwc<<<dim3(KROIS), dim3(512), 0, stream>>>(nhwc, rois, out);
    } else {
        const size_t total = (size_t)KROIS * CCH * NPIX;
        roi_align_naive<<<dim3((unsigned)((total + 255) / 256)), dim3(256), 0, stream>>>(feat, rois, out);
    }
}

// Round 3
// 55.857 us; speedup vs baseline: 1.7447x; 1.7447x over previous
//
#include <hip/hip_runtime.h>
#include <hip/hip_fp16.h>

#define NIMG 2
#define CCH 256
#define FH 128
#define FW 128
#define FHW (FH * FW)
#define OUTH 7
#define OUTW 7
#define NPIX 49
#define KROIS 1024
#define SCALE 0.0625f
#define OPITCH 260  // 49 rows x 260 floats; rotates banks between rows, float4-aligned

typedef float f32x4 __attribute__((ext_vector_type(4)));  // nontemporal-store-compatible

// ---------------- NCHW f32 -> NHWC fp16 transpose+convert ----------------
// per image: (256 c) x (16384 hw) f32  ->  (16384 hw) x (256 c) fp16
__global__ __launch_bounds__(256) void nchw_to_nhwc_h(const float* __restrict__ in,
                                                      __half* __restrict__ out) {
    __shared__ float tile[32][33];
    const int b   = blockIdx.z;
    const int hw0 = blockIdx.x << 5;
    const int c0  = blockIdx.y << 5;
    const int tx  = threadIdx.x;
    const int ty  = threadIdx.y;
    const float* src = in  + (size_t)b * CCH * FHW;
    __half*      dst = out + (size_t)b * FHW * CCH;
#pragma unroll
    for (int i = 0; i < 32; i += 8)
        tile[ty + i][tx] = src[(size_t)(c0 + ty + i) * FHW + hw0 + tx];
    __syncthreads();
#pragma unroll
    for (int i = 0; i < 32; i += 8)
        dst[(size_t)(hw0 + ty + i) * CCH + c0 + tx] = __float2half(tile[tx][ty + i]);
}

// ---------------- main RoIAlign on NHWC fp16 ----------------
__global__ __launch_bounds__(512) void roi_align_nhwc(const __half* __restrict__ nhwc,
                                                      const float* __restrict__ rois,
                                                      float* __restrict__ out) {
    __shared__ float obuf[NPIX * OPITCH];  // 50,960 B
    const int k    = blockIdx.x;
    const int lane = threadIdx.x & 63;
    const int wave = threadIdx.x >> 6;

    const float* r = rois + k * 5;
    const int b = (int)r[0];
    const float x1 = __fsub_rn(__fmul_rn(r[1], SCALE), 0.5f);
    const float y1 = __fsub_rn(__fmul_rn(r[2], SCALE), 0.5f);
    const float x2 = __fsub_rn(__fmul_rn(r[3], SCALE), 0.5f);
    const float y2 = __fsub_rn(__fmul_rn(r[4], SCALE), 0.5f);
    const float bw = __fdiv_rn(__fsub_rn(x2, x1), (float)OUTW);
    const float bh = __fdiv_rn(__fsub_rn(y2, y1), (float)OUTH);
    // lane owns channels [lane*4, lane*4+4)
    const __half* fb = nhwc + ((size_t)b * FHW << 8) + (lane << 2);

    for (int pix = wave; pix < NPIX; pix += 8) {
        const int ph = pix / 7;
        const int pw = pix - ph * 7;
        float acc0 = 0.f, acc1 = 0.f, acc2 = 0.f, acc3 = 0.f;
#pragma unroll
        for (int s = 0; s < 4; ++s) {
            const int sy = s >> 1, sx = s & 1;
            const float fy = (float)ph + (sy ? 0.75f : 0.25f);  // exact in f32
            const float fx = (float)pw + (sx ? 0.75f : 0.25f);  // exact in f32
            const float y = __fadd_rn(y1, __fmul_rn(fy, bh));   // match numpy rounding
            const float x = __fadd_rn(x1, __fmul_rn(fx, bw));
            if (y > -1.0f && y < (float)FH && x > -1.0f && x < (float)FW) {
                const float yc = fmaxf(y, 0.0f);
                const float xc = fmaxf(x, 0.0f);
                int y0 = (int)yc; if (y0 > FH - 1) y0 = FH - 1;
                int x0 = (int)xc; if (x0 > FW - 1) x0 = FW - 1;
                const int y1i = min(y0 + 1, FH - 1);
                const int x1i = min(x0 + 1, FW - 1);
                const float ly = fminf(yc - (float)y0, 1.0f);
                const float lx = fminf(xc - (float)x0, 1.0f);
                const float hy = 1.0f - ly, hx = 1.0f - lx;
                const float w00 = hy * hx, w01 = hy * lx, w10 = ly * hx, w11 = ly * lx;
                const uint2 r00 = *(const uint2*)(fb + ((size_t)(y0  * FW + x0 ) << 8));
                const uint2 r01 = *(const uint2*)(fb + ((size_t)(y0  * FW + x1i) << 8));
                const uint2 r10 = *(const uint2*)(fb + ((size_t)(y1i * FW + x0 ) << 8));
                const uint2 r11 = *(const uint2*)(fb + ((size_t)(y1i * FW + x1i) << 8));
                const float2 a00 = __half22float2(*(const __half2*)&r00.x);
                const float2 b00 = __half22float2(*(const __half2*)&r00.y);
                const float2 a01 = __half22float2(*(const __half2*)&r01.x);
                const float2 b01 = __half22float2(*(const __half2*)&r01.y);
                const float2 a10 = __half22float2(*(const __half2*)&r10.x);
                const float2 b10 = __half22float2(*(const __half2*)&r10.y);
                const float2 a11 = __half22float2(*(const __half2*)&r11.x);
                const float2 b11 = __half22float2(*(const __half2*)&r11.y);
                acc0 += w00 * a00.x + w01 * a01.x + w10 * a10.x + w11 * a11.x;
                acc1 += w00 * a00.y + w01 * a01.y + w10 * a10.y + w11 * a11.y;
                acc2 += w00 * b00.x + w01 * b01.x + w10 * b10.x + w11 * b11.x;
                acc3 += w00 * b00.y + w01 * b01.y + w10 * b10.y + w11 * b11.y;
            }
        }
        float4 res = make_float4(acc0 * 0.25f, acc1 * 0.25f, acc2 * 0.25f, acc3 * 0.25f);
        *(float4*)(&obuf[pix * OPITCH + (lane << 2)]) = res;
    }
    __syncthreads();

    // coalesced writeout: out[k][c][pix], 12544 contiguous floats per k.
    // non-temporal: don't let 50 MB of output evict the fp16 feature map from L2.
    float* op = out + (size_t)k * (CCH * NPIX);
    for (int f4 = threadIdx.x; f4 < (CCH * NPIX) / 4; f4 += 512) {
        const int f = f4 << 2;
        f32x4 o;
        {
            const int fi = f + 0; const int c = fi / NPIX; const int p = fi - c * NPIX;
            o.x = obuf[p * OPITCH + c];
        }
        {
            const int fi = f + 1; const int c = fi / NPIX; const int p = fi - c * NPIX;
            o.y = obuf[p * OPITCH + c];
        }
        {
            const int fi = f + 2; const int c = fi / NPIX; const int p = fi - c * NPIX;
            o.z = obuf[p * OPITCH + c];
        }
        {
            const int fi = f + 3; const int c = fi / NPIX; const int p = fi - c * NPIX;
            o.w = obuf[p * OPITCH + c];
        }
        __builtin_nontemporal_store(o, (f32x4*)(op + f));
    }
}

// ---------------- fallback: direct NCHW f32, one thread per output element ----------------
__global__ __launch_bounds__(256) void roi_align_naive(const float* __restrict__ feat,
                                                       const float* __restrict__ rois,
                                                       float* __restrict__ out) {
    const size_t idx = (size_t)blockIdx.x * 256 + threadIdx.x;
    const size_t total = (size_t)KROIS * CCH * NPIX;
    if (idx >= total) return;
    const int pix = (int)(idx % NPIX);
    const int t1  = (int)(idx / NPIX);
    const int c   = t1 % CCH;
    const int k   = t1 / CCH;
    const int ph = pix / 7;
    const int pw = pix - ph * 7;

    const float* r = rois + k * 5;
    const int b = (int)r[0];
    const float x1 = __fsub_rn(__fmul_rn(r[1], SCALE), 0.5f);
    const float y1 = __fsub_rn(__fmul_rn(r[2], SCALE), 0.5f);
    const float x2 = __fsub_rn(__fmul_rn(r[3], SCALE), 0.5f);
    const float y2 = __fsub_rn(__fmul_rn(r[4], SCALE), 0.5f);
    const float bw = __fdiv_rn(__fsub_rn(x2, x1), (float)OUTW);
    const float bh = __fdiv_rn(__fsub_rn(y2, y1), (float)OUTH);
    const float* fp = feat + (size_t)(b * CCH + c) * FHW;

    float acc = 0.f;
#pragma unroll
    for (int s = 0; s < 4; ++s) {
        const int sy = s >> 1, sx = s & 1;
        const float fy = (float)ph + (sy ? 0.75f : 0.25f);
        const float fx = (float)pw + (sx ? 0.75f : 0.25f);
        const float y = __fadd_rn(y1, __fmul_rn(fy, bh));
        const float x = __fadd_rn(x1, __fmul_rn(fx, bw));
        if (y > -1.0f && y < (float)FH && x > -1.0f && x < (float)FW) {
            const float yc = fmaxf(y, 0.0f);
            const float xc = fmaxf(x, 0.0f);
            int y0 = (int)yc; if (y0 > FH - 1) y0 = FH - 1;
            int x0 = (int)xc; if (x0 > FW - 1) x0 = FW - 1;
            const int y1i = min(y0 + 1, FH - 1);
            const int x1i = min(x0 + 1, FW - 1);
            const float ly = fminf(yc - (float)y0, 1.0f);
            const float lx = fminf(xc - (float)x0, 1.0f);
            const float hy = 1.0f - ly, hx = 1.0f - lx;
            acc += (hy * hx) * fp[y0  * FW + x0 ] + (hy * lx) * fp[y0  * FW + x1i]
                 + (ly * hx) * fp[y1i * FW + x0 ] + (ly * lx) * fp[y1i * FW + x1i];
        }
    }
    out[idx] = acc * 0.25f;
}

extern "C" void kernel_launch(void* const* d_in, const int* in_sizes, int n_in,
                              void* d_out, int out_size, void* d_ws, size_t ws_size,
                              hipStream_t stream) {
    const float* feat = (const float*)d_in[0];
    const float* rois = (const float*)d_in[1];
    float* out = (float*)d_out;

    const size_t nhwc_bytes = (size_t)NIMG * CCH * FHW * sizeof(__half);  // 16.8 MB
    if (ws_size >= nhwc_bytes) {
        __half* nhwc = (__half*)d_ws;
        dim3 tg(FHW / 32, CCH / 32, NIMG);
        nchw_to_nhwc_h<<<tg, dim3(32, 8), 0, stream>>>(feat, nhwc);
        roi_align_nhwc<<<dim3(KROIS), dim3(512), 0, stream>>>(nhwc, rois, out);
    } else {
        const size_t total = (size_t)KROIS * CCH * NPIX;
        roi_align_naive<<<dim3((unsigned)((total + 255) / 256)), dim3(256), 0, stream>>>(feat, rois, out);
    }
}